// Round 8
// baseline (760.262 us; speedup 1.0000x reference)
//
#include <hip/hip_runtime.h>
#include <hip/hip_bf16.h>

#define N_NODES 100000
#define N_EDGES 1600000
#define NBUCK 1563         // ceil(N/64): bucket = 64-node dst range
#define BCAP 1216          // per-bucket capacity (mean 1024, +6 sigma)
#define PADC 1408          // LDS ssrc capacity incl. per-node x4 padding
#define ACHUNK 4096        // edges per partA block
#define GTILES 1563        // gemm row tiles (= NBUCK)
#define PABLK 391          // ceil(E/ACHUNK) partA units
#define WUNITS (GTILES + PABLK)

typedef __bf16 bf16x8 __attribute__((ext_vector_type(8)));
typedef __bf16 bf16x4 __attribute__((ext_vector_type(4)));
typedef float  f32x4  __attribute__((ext_vector_type(4)));
typedef float  f32x2  __attribute__((ext_vector_type(2)));

// Feature permutation for P/R rows: feature f lives at position
// pos(f) = (f&15)*8 + (f>>4); inverse f(pos) = ((pos&7)<<4) | (pos>>3).
// P1/P2 have N+1 rows: row N is an all-zero sentinel for padded edge slots.
//
// R20 (dispatch-gap insight): summed kernel durs ~165 µs vs bench 227-243 —
// ~15 µs per dispatch boundary (barrier packet + cross-XCD L2 flush). Fix:
// ONE persistent kernel, software grid barriers (device-scope atomics +
// threadfence, guide G16), phases init->work1->fusedB->fusedC. Grid sized
// by occupancy query (cap 4/CU) so all blocks co-resident; spin bounded.
// R19: AGPR carve is kernel-wide -> gather phases live under arch cap
// 128-32=96; 4-deep uint4 gathers (~84 arch) fit.
// R7 null: H round-trip split was net-negative; fusedB stays fused.
// R5/R7: work1 W-prefetch regressed (53.5->58.5); reverted to JIT loads.

// fp8x16 (uint4) -> 16 f32 accumulate
#define ACC16(v)                                             \
  a01 += __builtin_amdgcn_cvt_pk_f32_fp8((v).x, false);      \
  a23 += __builtin_amdgcn_cvt_pk_f32_fp8((v).x, true);       \
  a45 += __builtin_amdgcn_cvt_pk_f32_fp8((v).y, false);      \
  a67 += __builtin_amdgcn_cvt_pk_f32_fp8((v).y, true);       \
  a89 += __builtin_amdgcn_cvt_pk_f32_fp8((v).z, false);      \
  aAB += __builtin_amdgcn_cvt_pk_f32_fp8((v).z, true);       \
  aCD += __builtin_amdgcn_cvt_pk_f32_fp8((v).w, false);      \
  aEF += __builtin_amdgcn_cvt_pk_f32_fp8((v).w, true);

__device__ __forceinline__ bf16x8 wfrag(const __bf16* Wswz, int w, int lane, int ct, int c) {
  return *(const bf16x8*)&Wswz[(size_t)((((w * 4 + ct) * 4 + c) * 64) + lane) * 8];
}

// -------- software grid barrier (monotonic counter; all blocks resident) --------
__device__ __forceinline__ void grid_barrier(int* bar, int target) {
  __syncthreads();
  if (threadIdx.x == 0) {
    __threadfence();   // release: prior writes visible device-wide
    __hip_atomic_fetch_add(bar, 1, __ATOMIC_ACQ_REL, __HIP_MEMORY_SCOPE_AGENT);
    int spins = 0;
    while (__hip_atomic_load(bar, __ATOMIC_ACQUIRE, __HIP_MEMORY_SCOPE_AGENT) < target) {
      __builtin_amdgcn_s_sleep(32);
      if (++spins > 4000000) break;   // safety valve: fail fast, never hang
    }
    __threadfence();   // acquire: invalidate stale cached lines
  }
  __syncthreads();
}

// ---------------- phase 0: init (zero bcnt/sentinels) + weight swizzle ----------------

__device__ __forceinline__ void dev_init(int u, int t, int* bcnt, int* P1s, int* P2s,
    const float* Wl1, const float* Wr1, const float* Wl2, const float* Wr2,
    __bf16* W1out, __bf16* W2out) {
  if (u == 0) {
    for (int i = t; i < NBUCK; i += 256) bcnt[i] = 0;
    if (t < 32) { P1s[t] = 0; P2s[t] = 0; }   // 128 B fp8 sentinel rows
    return;
  }
  int gi = (u - 1) * 256 + t;                 // 0..65535
  bool L2 = gi >= 32768;
  int i = gi & 32767;
  int j = i & 7;
  int lane = (i >> 3) & 63;
  int c = (i >> 9) & 3;
  int tile = i >> 11;
  int k = c * 32 + ((lane >> 4) * 8) + j;
  int krow = L2 ? (((k & 7) << 4) | (k >> 3)) : k;
  int col = tile * 16 + (lane & 15);
  const float* Wl = L2 ? Wl2 : Wl1;
  const float* Wr = L2 ? Wr2 : Wr1;
  float v = (col < 128) ? Wl[krow * 128 + col] : Wr[krow * 128 + (col - 128)];
  (L2 ? W2out : W1out)[i] = (__bf16)v;
}

// ---------------- phase 1: partA (u<PABLK) | gemm1 tile (u-PABLK) ----------------

__device__ __forceinline__ void dev_work1(int u, int t, char* smem,
    const float* A, const __bf16* Wswz, const float* bias,
    unsigned char* P, __bf16* R, int M,
    const int* src, const int* dst, int* bcnt, unsigned* packed, int E) {
  __syncthreads();                            // LDS reuse guard across units
  if (u < PABLK) {
    int* hist = (int*)smem;                   // NBUCK ints
    int* curs = (int*)(smem + 6272);
    for (int i = t; i < NBUCK; i += 256) hist[i] = 0;
    __syncthreads();

    const int base = u * ACHUNK;
    const int lim = min(base + ACHUNK, E);
    int dloc[16], sloc[16];
    int myn = 0;
    for (int i = base + t; i < lim; i += 256) {
      dloc[myn] = dst[i];
      sloc[myn] = src[i];
      ++myn;
    }
    for (int k = 0; k < myn; ++k) atomicAdd(&hist[dloc[k] >> 6], 1);
    __syncthreads();

    for (int i = t; i < NBUCK; i += 256) {
      int h = hist[i];
      curs[i] = (h > 0) ? atomicAdd(&bcnt[i], h) : 0;
    }
    __syncthreads();

    for (int k = 0; k < myn; ++k) {
      int d = dloc[k];
      int b = d >> 6;
      int pos = atomicAdd(&curs[b], 1);
      if (pos < BCAP)
        packed[(size_t)b * BCAP + pos] = ((unsigned)sloc[k] << 6) | (unsigned)(d & 63);
    }
    return;
  }

  // gemm1 tile
  __bf16 (*ldsA)[144] = (__bf16 (*)[144])smem;
  const int lane = t & 63;
  const int w = t >> 6;
  const int q = lane >> 4;
  const int s = lane & 15;
  const int m0 = (u - PABLK) * 64;

#pragma unroll
  for (int it = 0; it < 8; ++it) {
    int row = it * 8 + (t >> 5);
    int col = (t & 31) * 4;
    float4 v = make_float4(0.f, 0.f, 0.f, 0.f);
    if (m0 + row < M) v = *(const float4*)&A[(size_t)(m0 + row) * 128 + col];
    bf16x4 bv;
    bv.x = (__bf16)v.x; bv.y = (__bf16)v.y; bv.z = (__bf16)v.z; bv.w = (__bf16)v.w;
    *(bf16x4*)&ldsA[row][col] = bv;
  }

  float breg[4];
#pragma unroll
  for (int j = 0; j < 4; ++j)
    breg[j] = (w >= 2) ? bias[((w - 2) * 4 + j) * 16 + s] : 0.f;

  __syncthreads();

#pragma unroll
  for (int half = 0; half < 2; ++half) {
    f32x4 acc[8];
    f32x4 zero = {0.f, 0.f, 0.f, 0.f};
#pragma unroll
    for (int i = 0; i < 8; ++i) acc[i] = zero;

#pragma unroll
    for (int c = 0; c < 4; ++c) {
      bf16x8 a0 = *(const bf16x8*)&ldsA[(half * 2 + 0) * 16 + s][c * 32 + q * 8];
      bf16x8 a1 = *(const bf16x8*)&ldsA[(half * 2 + 1) * 16 + s][c * 32 + q * 8];
#pragma unroll
      for (int ct = 0; ct < 4; ++ct) {
        bf16x8 b = wfrag(Wswz, w, lane, ct, c);
        acc[ct]     = __builtin_amdgcn_mfma_f32_16x16x32_bf16(a0, b, acc[ct], 0, 0, 0);
        acc[4 + ct] = __builtin_amdgcn_mfma_f32_16x16x32_bf16(a1, b, acc[4 + ct], 0, 0, 0);
      }
    }

#pragma unroll
    for (int i = 0; i < 2; ++i) {
      int rt = half * 2 + i;
#pragma unroll
      for (int r = 0; r < 4; ++r) {
        int row = m0 + rt * 16 + q * 4 + r;
        if (row < M) {
          if (w < 2) {
            unsigned v = 0;
            v = __builtin_amdgcn_cvt_pk_fp8_f32(acc[i * 4 + 0][r], acc[i * 4 + 1][r], v, false);
            v = __builtin_amdgcn_cvt_pk_fp8_f32(acc[i * 4 + 2][r], acc[i * 4 + 3][r], v, true);
            *(unsigned*)&P[(size_t)row * 128 + s * 8 + w * 4] = v;
          } else {
            bf16x4 o;
#pragma unroll
            for (int ct = 0; ct < 4; ++ct) o[ct] = (__bf16)(acc[i * 4 + ct][r] + breg[ct]);
            *(bf16x4*)&R[(size_t)row * 128 + s * 8 + (w - 2) * 4] = o;
          }
        }
      }
    }
  }
}

// ---------------- phase 2: fusedB bucket (sort + dump + gather + GEMM) ----------------

__device__ __forceinline__ void dev_fusedB(int b, int t, char* smem,
    const unsigned char* P1, __bf16* R, const unsigned* pck, const int* bcnt,
    const __bf16* Wswz, const float* bias, unsigned char* P2,
    int* srt, int* meta, int N) {
  __bf16 (*Hlds)[144] = (__bf16 (*)[144])smem;     // 18432 B
  int* ssrcL = (int*)(smem + 18432);               // 5632 B
  int* hist  = (int*)(smem + 24064);
  int* pexcl = (int*)(smem + 24320);
  int* curs  = (int*)(smem + 24576);
  int* scanb = (int*)(smem + 24832);
  int* gst   = (int*)(smem + 25088);
  const int lane = t & 63;
  const int w = t >> 6;
  const int q = lane >> 4;
  const int s = lane & 15;
  const int nb = b * 64;

  __syncthreads();                            // LDS reuse guard across units
  if (t < 64) hist[t] = 0;
  if (t == 0) *gst = 0;
  __syncthreads();

  const int ecnt = min(bcnt[b], BCAP);
  const unsigned* pk = pck + (size_t)b * BCAP;
  unsigned ploc[5];
  int myn = 0;
  for (int i = t; i < ecnt; i += 256) {
    unsigned p = pk[i];
    ploc[myn++] = p;
    atomicAdd(&hist[p & 63u], 1);
  }
  __syncthreads();

  int c0 = (t < 64) ? hist[t] : 0;
  int pc = (c0 + 3) & ~3;
  int x = pc;
  if (t < 64) scanb[t] = x;
  __syncthreads();
  for (int d = 1; d < 64; d <<= 1) {
    int y = (t >= d && t < 64) ? scanb[t - d] : 0;
    __syncthreads();
    if (t < 64) { x += y; scanb[t] = x; }
    __syncthreads();
  }
  if (t < 64) { pexcl[t] = x - pc; curs[t] = x - pc; }
  __syncthreads();

  for (int k = 0; k < myn; ++k) {
    unsigned p = ploc[k];
    int r = atomicAdd(&curs[p & 63u], 1);
    ssrcL[r] = (int)(p >> 6);
  }
  if (t < 64)
    for (int j = c0; j < pc; ++j) ssrcL[pexcl[t] + j] = N;   // disjoint pad slots
  __syncthreads();

  // dump sorted list + meta for fusedC
  for (int i = t; i < PADC; i += 256) srt[(size_t)b * PADC + i] = ssrcL[i];
  if (t < 64) meta[b * 64 + t] = (pexcl[t] << 16) | hist[t];

  // steal-gather: each wave grabs 8 nodes (one per 8-lane group); 4-deep uint4
  const int s8 = lane & 7;
  const int g8 = lane >> 3;
  const unsigned char* Pb = P1 + (size_t)s8 * 16;
  for (;;) {
    int n8;
    if (lane == 0) n8 = atomicAdd(gst, 8);
    n8 = __shfl(n8, 0, 64);
    if (n8 >= 64) break;
    int dl = n8 + g8;
    int node = nb + dl;
    int start = pexcl[dl];
    int dg = hist[dl];
    int pend = start + ((dg + 3) & ~3);

    f32x2 a01 = {0.f, 0.f}, a23 = {0.f, 0.f}, a45 = {0.f, 0.f}, a67 = {0.f, 0.f};
    f32x2 a89 = {0.f, 0.f}, aAB = {0.f, 0.f}, aCD = {0.f, 0.f}, aEF = {0.f, 0.f};
    for (int cur = start; cur < pend; cur += 4) {
      int4 sv = *(const int4*)&ssrcL[cur];    // LDS broadcast (16B-aligned)
      uint4 v0 = *(const uint4*)(Pb + (size_t)sv.x * 128);
      uint4 v1 = *(const uint4*)(Pb + (size_t)sv.y * 128);
      uint4 v2 = *(const uint4*)(Pb + (size_t)sv.z * 128);
      uint4 v3 = *(const uint4*)(Pb + (size_t)sv.w * 128);
      ACC16(v0) ACC16(v1) ACC16(v2) ACC16(v3)
    }

    int nc = min(node, N - 1);
    float inv = 1.0f / (float)(dg > 0 ? dg : 1);
    const int p16 = s8 * 16;
    bf16x8 rv0 = *(const bf16x8*)&R[(size_t)nc * 128 + p16];
    bf16x8 rv1 = *(const bf16x8*)&R[(size_t)nc * 128 + p16 + 8];
    float ac[16] = {a01[0], a01[1], a23[0], a23[1], a45[0], a45[1], a67[0], a67[1],
                    a89[0], a89[1], aAB[0], aAB[1], aCD[0], aCD[1], aEF[0], aEF[1]};
    bf16x8 h0, h1;
#pragma unroll
    for (int j = 0; j < 8; ++j) {
      h0[j] = (__bf16)fmaxf(ac[j] * inv + (float)rv0[j], 0.f);
      h1[j] = (__bf16)fmaxf(ac[8 + j] * inv + (float)rv1[j], 0.f);
    }
    *(bf16x8*)&Hlds[dl][p16] = h0;
    *(bf16x8*)&Hlds[dl][p16 + 8] = h1;
  }
  __syncthreads();

  float breg[4];
#pragma unroll
  for (int j = 0; j < 4; ++j)
    breg[j] = (w >= 2) ? bias[((w - 2) * 4 + j) * 16 + s] : 0.f;

  // GEMM: [P2|R2] = H @ Ws2 (+b2)
#pragma unroll
  for (int half = 0; half < 2; ++half) {
    f32x4 acc[8];
    f32x4 zero = {0.f, 0.f, 0.f, 0.f};
#pragma unroll
    for (int i = 0; i < 8; ++i) acc[i] = zero;

#pragma unroll
    for (int c = 0; c < 4; ++c) {
      bf16x8 a0 = *(const bf16x8*)&Hlds[(half * 2 + 0) * 16 + s][c * 32 + q * 8];
      bf16x8 a1 = *(const bf16x8*)&Hlds[(half * 2 + 1) * 16 + s][c * 32 + q * 8];
#pragma unroll
      for (int ct = 0; ct < 4; ++ct) {
        bf16x8 bb = wfrag(Wswz, w, lane, ct, c);
        acc[ct]     = __builtin_amdgcn_mfma_f32_16x16x32_bf16(a0, bb, acc[ct], 0, 0, 0);
        acc[4 + ct] = __builtin_amdgcn_mfma_f32_16x16x32_bf16(a1, bb, acc[4 + ct], 0, 0, 0);
      }
    }

#pragma unroll
    for (int i = 0; i < 2; ++i) {
      int rt = half * 2 + i;
#pragma unroll
      for (int r = 0; r < 4; ++r) {
        int row = nb + rt * 16 + q * 4 + r;
        if (row < N) {
          if (w < 2) {
            unsigned v = 0;
            v = __builtin_amdgcn_cvt_pk_fp8_f32(acc[i * 4 + 0][r], acc[i * 4 + 1][r], v, false);
            v = __builtin_amdgcn_cvt_pk_fp8_f32(acc[i * 4 + 2][r], acc[i * 4 + 3][r], v, true);
            *(unsigned*)&P2[(size_t)row * 128 + s * 8 + w * 4] = v;
          } else {
            bf16x4 o;
#pragma unroll
            for (int ct = 0; ct < 4; ++ct) o[ct] = (__bf16)(acc[i * 4 + ct][r] + breg[ct]);
            *(bf16x4*)&R[(size_t)row * 128 + s * 8 + (w - 2) * 4] = o;
          }
        }
      }
    }
  }
}

// ---------------- phase 3: fusedC bucket (presorted gather + heads) ----------------

__device__ __forceinline__ void dev_fusedC(int b, int t, char* smem,
    const unsigned char* P2, const __bf16* R, const int* srt, const int* meta,
    float* out, const float* Wp, const float* Wd,
    const float* bp, const float* bd, int N) {
  int* ssrcL = (int*)smem;                   // 5632 B
  int* hist  = (int*)(smem + 5632);
  int* pexcl = (int*)(smem + 5888);
  int* gst   = (int*)(smem + 6144);
  const int lane = t & 63;
  const int nb = b * 64;

  __syncthreads();                            // LDS reuse guard across units
  for (int i = t; i < PADC; i += 256) ssrcL[i] = srt[(size_t)b * PADC + i];
  if (t < 64) {
    int m = meta[b * 64 + t];
    pexcl[t] = m >> 16;
    hist[t] = m & 0xffff;
  }
  if (t == 0) *gst = 0;
  __syncthreads();

  const int s8 = lane & 7;
  const int g8 = lane >> 3;
  const unsigned char* Pb = P2 + (size_t)s8 * 16;
  for (;;) {
    int n8;
    if (lane == 0) n8 = atomicAdd(gst, 8);
    n8 = __shfl(n8, 0, 64);
    if (n8 >= 64) break;
    int dl = n8 + g8;
    int node = nb + dl;
    int start = pexcl[dl];
    int dg = hist[dl];
    int pend = start + ((dg + 3) & ~3);

    f32x2 a01 = {0.f, 0.f}, a23 = {0.f, 0.f}, a45 = {0.f, 0.f}, a67 = {0.f, 0.f};
    f32x2 a89 = {0.f, 0.f}, aAB = {0.f, 0.f}, aCD = {0.f, 0.f}, aEF = {0.f, 0.f};
    for (int cur = start; cur < pend; cur += 4) {
      int4 sv = *(const int4*)&ssrcL[cur];
      uint4 v0 = *(const uint4*)(Pb + (size_t)sv.x * 128);
      uint4 v1 = *(const uint4*)(Pb + (size_t)sv.y * 128);
      uint4 v2 = *(const uint4*)(Pb + (size_t)sv.z * 128);
      uint4 v3 = *(const uint4*)(Pb + (size_t)sv.w * 128);
      ACC16(v0) ACC16(v1) ACC16(v2) ACC16(v3)
    }

    int nc = min(node, N - 1);
    float inv = 1.0f / (float)(dg > 0 ? dg : 1);
    const int p16 = s8 * 16;
    bf16x8 rv0 = *(const bf16x8*)&R[(size_t)nc * 128 + p16];
    bf16x8 rv1 = *(const bf16x8*)&R[(size_t)nc * 128 + p16 + 8];
    float ac[16] = {a01[0], a01[1], a23[0], a23[1], a45[0], a45[1], a67[0], a67[1],
                    a89[0], a89[1], aAB[0], aAB[1], aCD[0], aCD[1], aEF[0], aEF[1]};
    float p = 0.f, dd = 0.f;
#pragma unroll
    for (int j = 0; j < 16; ++j) {
      int pos = p16 + j;
      int f = ((pos & 7) << 4) | (pos >> 3);   // inverse feature perm
      float rvj = (float)((j < 8) ? rv0[j] : rv1[j - 8]);
      float h = fmaxf(ac[j] * inv + rvj, 0.f);
      p += h * Wp[f];
      dd += h * Wd[f];
    }
    p += __shfl_xor(p, 1, 64);  p += __shfl_xor(p, 2, 64);  p += __shfl_xor(p, 4, 64);
    dd += __shfl_xor(dd, 1, 64); dd += __shfl_xor(dd, 2, 64); dd += __shfl_xor(dd, 4, 64);
    if (node < N && s8 == 0) {
      float preds = p + bp[0];
      float sg = 1.0f / (1.0f + __expf(-(dd + bd[0])));
      out[node] = preds - sg;
      out[N + node] = preds + sg;
    }
  }
}

// ----------------------------------- mega kernel -----------------------------------

__global__ __launch_bounds__(256, 4) void mega_kernel(
    int* __restrict__ bar,
    const float* __restrict__ x, const int* __restrict__ src, const int* __restrict__ dst,
    const float* __restrict__ Wl1, const float* __restrict__ Wr1, const float* __restrict__ b1,
    const float* __restrict__ Wl2, const float* __restrict__ Wr2, const float* __restrict__ b2,
    const float* __restrict__ Wp, const float* __restrict__ bp,
    const float* __restrict__ Wd, const float* __restrict__ bd,
    unsigned char* __restrict__ P1, unsigned char* __restrict__ P2, __bf16* __restrict__ Rbuf,
    unsigned* __restrict__ pck, int* __restrict__ bcnt,
    __bf16* __restrict__ Ws1, __bf16* __restrict__ Ws2,
    int* __restrict__ srt, int* __restrict__ meta, float* __restrict__ out,
    int N, int E) {
  __shared__ __align__(16) char smem[25600];
  const int t = threadIdx.x;
  const int G = gridDim.x;

  // phase 0: init + weight swizzle
  for (int u = blockIdx.x; u < 257; u += G)
    dev_init(u, t, bcnt, (int*)(P1 + (size_t)N * 128), (int*)(P2 + (size_t)N * 128),
             Wl1, Wr1, Wl2, Wr2, Ws1, Ws2);
  grid_barrier(bar, 1 * G);

  // phase 1: partA || gemm1
  for (int u = blockIdx.x; u < WUNITS; u += G)
    dev_work1(u, t, smem, x, Ws1, b1, P1, Rbuf, N, src, dst, bcnt, pck, E);
  grid_barrier(bar, 2 * G);

  // phase 2: fusedB per bucket
  for (int u = blockIdx.x; u < NBUCK; u += G)
    dev_fusedB(u, t, smem, P1, Rbuf, pck, bcnt, Ws2, b2, P2, srt, meta, N);
  grid_barrier(bar, 3 * G);

  // phase 3: fusedC per bucket
  for (int u = blockIdx.x; u < NBUCK; u += G)
    dev_fusedC(u, t, smem, P2, Rbuf, srt, meta, out, Wp, Wd, bp, bd, N);
}

// ----------------------------------- launch -----------------------------------

extern "C" void kernel_launch(void* const* d_in, const int* in_sizes, int n_in,
                              void* d_out, int out_size, void* d_ws, size_t ws_size,
                              hipStream_t stream) {
  const float* x    = (const float*)d_in[0];
  const int*   ei   = (const int*)d_in[1];
  const float* Wl1 = (const float*)d_in[2];
  const float* Wr1 = (const float*)d_in[3];
  const float* b1  = (const float*)d_in[4];
  const float* Wl2 = (const float*)d_in[5];
  const float* Wr2 = (const float*)d_in[6];
  const float* b2  = (const float*)d_in[7];
  const float* Wp  = (const float*)d_in[8];
  const float* bp  = (const float*)d_in[9];
  const float* Wd  = (const float*)d_in[10];
  const float* bd  = (const float*)d_in[11];
  float* out = (float*)d_out;

  const int N = N_NODES, E = N_EDGES;
  const int* src = ei;
  const int* dst = ei + E;

  char* w = (char*)d_ws;
  int* bar       = (int*)w;      w += 64;                             // barrier cell
  unsigned char* P1 = (unsigned char*)w; w += (size_t)(N + 1) * 128;  // fp8 + sentinel
  unsigned char* P2 = (unsigned char*)w; w += (size_t)(N + 1) * 128;  // fp8 + sentinel
  __bf16* Rbuf   = (__bf16*)w;   w += (size_t)N * 128 * 2;            // R1 -> R2 in place
  unsigned* pck  = (unsigned*)w; w += (size_t)NBUCK * BCAP * 4;       // 7.6 MB
  int* bcnt      = (int*)w;      w += (size_t)(NBUCK + 32) * 4;
  __bf16* Ws1    = (__bf16*)w;   w += 65536;
  __bf16* Ws2    = (__bf16*)w;   w += 65536;
  int* srt       = (int*)w;      w += (size_t)NBUCK * PADC * 4;       // 8.8 MB
  int* meta      = (int*)w;      w += (size_t)NBUCK * 64 * 4;         // 0.4 MB

  // co-residency-safe grid: occupancy query, capped at 4 blocks/CU
  static int blocksPerCU = 0;
  if (blocksPerCU == 0) {
    int nb = 0;
    if (hipOccupancyMaxActiveBlocksPerMultiprocessor(&nb, mega_kernel, 256, 0) != hipSuccess || nb < 1)
      nb = 2;                                   // conservative fallback
    blocksPerCU = nb > 4 ? 4 : nb;
  }
  const int grid = blocksPerCU * 256;

  hipMemsetAsync(bar, 0, 64, stream);           // zero barrier counter
  mega_kernel<<<grid, 256, 0, stream>>>(bar, x, src, dst,
                                        Wl1, Wr1, b1, Wl2, Wr2, b2,
                                        Wp, bp, Wd, bd,
                                        P1, P2, Rbuf, pck, bcnt, Ws1, Ws2,
                                        srt, meta, out, N, E);
}

// Round 9
// 264.470 us; speedup vs baseline: 2.8747x; 2.8747x over previous
//
#include <hip/hip_runtime.h>
#include <hip/hip_bf16.h>

#define N_NODES 100000
#define N_EDGES 1600000
#define NBUCK 1563         // ceil(N/64): bucket = 64-node dst range
#define BCAP 1216          // per-bucket capacity (mean 1024, +6 sigma)
#define PADC 1408          // LDS ssrc capacity incl. per-node x4 padding
#define ACHUNK 16384       // edges per partA block (R21: big chunks -> ~10.5
                           // consecutive pck slots/bucket -> kills 6x write amp)
#define GTILES 1563        // gemm row tiles (= NBUCK)
#define PABLK 98           // ceil(E/ACHUNK) partA blocks

typedef __bf16 bf16x8 __attribute__((ext_vector_type(8)));
typedef __bf16 bf16x4 __attribute__((ext_vector_type(4)));
typedef float  f32x4  __attribute__((ext_vector_type(4)));
typedef float  f32x2  __attribute__((ext_vector_type(2)));

// Feature permutation for P/R rows: feature f lives at position
// pos(f) = (f&15)*8 + (f>>4); inverse f(pos) = ((pos&7)<<4) | (pos>>3).
// P1/P2 have N+1 rows: row N is an all-zero sentinel for padded edge slots.
//
// Session ledger:
// R13/R14/R17: any launch bound >4 waves/SIMD spills MFMA kernels (AGPR
//   carve shrinks arch budget). (256,6) is ONLY safe for MFMA-free kernels.
// R20 (mega kernel): persistent kernel = ONE regalloc across phases ->
//   VGPR 64 forced, 190MB scratch, 760 µs. Persistent path dead.
// R16/R18 nulls: partA grid position; gather batch depth (uint2); sort cost.
// R5/R7: work1 W-prefetch regressed (+3-5 µs) -> JIT W loads.
// R19: fusedB uint4 8-lane gather (8 rows/load-inst) helped; kept.
// R21 (this round): partA two-pass big-chunk: pck scatter was ~6x
//   write-amplified (2.6 slots/bucket/chunk -> partial 64B lines).

// fp8x16 (uint4) -> 16 f32 accumulate
#define ACC16(v)                                             \
  a01 += __builtin_amdgcn_cvt_pk_f32_fp8((v).x, false);      \
  a23 += __builtin_amdgcn_cvt_pk_f32_fp8((v).x, true);       \
  a45 += __builtin_amdgcn_cvt_pk_f32_fp8((v).y, false);      \
  a67 += __builtin_amdgcn_cvt_pk_f32_fp8((v).y, true);       \
  a89 += __builtin_amdgcn_cvt_pk_f32_fp8((v).z, false);      \
  aAB += __builtin_amdgcn_cvt_pk_f32_fp8((v).z, true);       \
  aCD += __builtin_amdgcn_cvt_pk_f32_fp8((v).w, false);      \
  aEF += __builtin_amdgcn_cvt_pk_f32_fp8((v).w, true);

// ---------------- K1: init (zero bcnt/sentinels) + weight swizzle ----------------

__global__ __launch_bounds__(256) void init_kernel(int* __restrict__ bcnt,
                                                   int* __restrict__ P1s,
                                                   int* __restrict__ P2s,
                                                   const float* __restrict__ Wl1,
                                                   const float* __restrict__ Wr1,
                                                   const float* __restrict__ Wl2,
                                                   const float* __restrict__ Wr2,
                                                   __bf16* __restrict__ W1out,
                                                   __bf16* __restrict__ W2out) {
  const int b = blockIdx.x, t = threadIdx.x;
  if (b == 0) {
    for (int i = t; i < NBUCK; i += 256) bcnt[i] = 0;
    if (t < 32) { P1s[t] = 0; P2s[t] = 0; }   // 128 B fp8 sentinel rows
    return;
  }
  int gi = (b - 1) * 256 + t;                 // 0..65535
  bool L2 = gi >= 32768;
  int i = gi & 32767;
  int j = i & 7;
  int lane = (i >> 3) & 63;
  int c = (i >> 9) & 3;
  int tile = i >> 11;
  int k = c * 32 + ((lane >> 4) * 8) + j;
  int krow = L2 ? (((k & 7) << 4) | (k >> 3)) : k;
  int col = tile * 16 + (lane & 15);
  const float* Wl = L2 ? Wl2 : Wl1;
  const float* Wr = L2 ? Wr2 : Wr1;
  float v = (col < 128) ? Wl[krow * 128 + col] : Wr[krow * 128 + (col - 128)];
  (L2 ? W2out : W1out)[i] = (__bf16)v;
}

// ------- K2: blocks 0..PABLK-1: partA (two-pass) ; blocks PABLK..: gemm1 -------

__global__ __launch_bounds__(256, 4) void work1_kernel(
    const float* __restrict__ A, const __bf16* __restrict__ Wswz,
    const float* __restrict__ bias, unsigned char* __restrict__ P,
    __bf16* __restrict__ R, int M,
    const int* __restrict__ src, const int* __restrict__ dst,
    int* __restrict__ bcnt, unsigned* __restrict__ packed, int E) {
  __shared__ __align__(16) char smem[64 * 144 * 2];   // 18432 B, unioned
  const int t = threadIdx.x;

  if (blockIdx.x < PABLK) {
    // ---- partA v2: two-pass big chunk (16384 edges) ----
    // pass 1: stream dst -> LDS histogram (no per-thread edge storage)
    int* hist = (int*)smem;                 // NBUCK ints = 6252 B
    int* curs = (int*)(smem + 6272);        // NBUCK ints
    for (int i = t; i < NBUCK; i += 256) hist[i] = 0;
    __syncthreads();

    const int base = blockIdx.x * ACHUNK;
    const int lim = min(base + ACHUNK, E);

    for (int i = base + t; i < lim; i += 256)
      atomicAdd(&hist[dst[i] >> 6], 1);
    __syncthreads();

    // one contiguous reservation per bucket per chunk (~10.5 slots avg)
    for (int i = t; i < NBUCK; i += 256) {
      int h = hist[i];
      curs[i] = (h > 0) ? atomicAdd(&bcnt[i], h) : 0;
    }
    __syncthreads();

    // pass 2: re-read edges, write into the chunk's consecutive runs
    for (int i = base + t; i < lim; i += 256) {
      int d = dst[i];
      int b = d >> 6;
      int pos = atomicAdd(&curs[b], 1);
      if (pos < BCAP)
        packed[(size_t)b * BCAP + pos] = ((unsigned)src[i] << 6) | (unsigned)(d & 63);
    }
    return;
  }

  // ---- gemm1 path (R4 form: JIT W loads, no prefetch) ----
  __bf16 (*ldsA)[144] = (__bf16 (*)[144])smem;
  const int lane = t & 63;
  const int w = t >> 6;
  const int q = lane >> 4;
  const int s = lane & 15;
  const int m0 = (blockIdx.x - PABLK) * 64;

#pragma unroll
  for (int it = 0; it < 8; ++it) {
    int row = it * 8 + (t >> 5);
    int col = (t & 31) * 4;
    float4 v = make_float4(0.f, 0.f, 0.f, 0.f);
    if (m0 + row < M) v = *(const float4*)&A[(size_t)(m0 + row) * 128 + col];
    bf16x4 bv;
    bv.x = (__bf16)v.x; bv.y = (__bf16)v.y; bv.z = (__bf16)v.z; bv.w = (__bf16)v.w;
    *(bf16x4*)&ldsA[row][col] = bv;
  }

  float breg[4];
#pragma unroll
  for (int j = 0; j < 4; ++j)
    breg[j] = (w >= 2) ? bias[((w - 2) * 4 + j) * 16 + s] : 0.f;

  __syncthreads();

#pragma unroll
  for (int half = 0; half < 2; ++half) {
    f32x4 acc[8];                       // 2 row-tiles x 4 col-tiles
    f32x4 zero = {0.f, 0.f, 0.f, 0.f};
#pragma unroll
    for (int i = 0; i < 8; ++i) acc[i] = zero;

#pragma unroll
    for (int c = 0; c < 4; ++c) {
      bf16x8 a0 = *(const bf16x8*)&ldsA[(half * 2 + 0) * 16 + s][c * 32 + q * 8];
      bf16x8 a1 = *(const bf16x8*)&ldsA[(half * 2 + 1) * 16 + s][c * 32 + q * 8];
#pragma unroll
      for (int ct = 0; ct < 4; ++ct) {
        bf16x8 b = *(const bf16x8*)&Wswz[(size_t)((((w * 4 + ct) * 4 + c) * 64) + lane) * 8];
        acc[ct]     = __builtin_amdgcn_mfma_f32_16x16x32_bf16(a0, b, acc[ct], 0, 0, 0);
        acc[4 + ct] = __builtin_amdgcn_mfma_f32_16x16x32_bf16(a1, b, acc[4 + ct], 0, 0, 0);
      }
    }

#pragma unroll
    for (int i = 0; i < 2; ++i) {
      int rt = half * 2 + i;
#pragma unroll
      for (int r = 0; r < 4; ++r) {
        int row = m0 + rt * 16 + q * 4 + r;
        if (row < M) {
          if (w < 2) {
            unsigned v = 0;
            v = __builtin_amdgcn_cvt_pk_fp8_f32(acc[i * 4 + 0][r], acc[i * 4 + 1][r], v, false);
            v = __builtin_amdgcn_cvt_pk_fp8_f32(acc[i * 4 + 2][r], acc[i * 4 + 3][r], v, true);
            *(unsigned*)&P[(size_t)row * 128 + s * 8 + w * 4] = v;
          } else {
            bf16x4 o;
#pragma unroll
            for (int ct = 0; ct < 4; ++ct) o[ct] = (__bf16)(acc[i * 4 + ct][r] + breg[ct]);
            *(bf16x4*)&R[(size_t)row * 128 + s * 8 + (w - 2) * 4] = o;
          }
        }
      }
    }
  }
}

// ------- K3: fusedB: sort + dump + 8-lane uint4 steal-gather(P1) -> H1 -> [P2|R2] -------

__global__ __launch_bounds__(256, 4) void fusedB_kernel(
    const unsigned char* __restrict__ P1, __bf16* R,
    const unsigned* __restrict__ pck, const int* __restrict__ bcnt,
    const __bf16* __restrict__ Wswz, const float* __restrict__ bias,
    unsigned char* __restrict__ P2, int* __restrict__ srt,
    int* __restrict__ meta, int N) {
  __shared__ __bf16 Hlds[64][144];
  __shared__ int ssrcL[PADC];
  __shared__ int hist[64], pexcl[64], curs[64], scanb[64];
  __shared__ int gsteal;
  const int t = threadIdx.x;
  const int lane = t & 63;
  const int w = t >> 6;
  const int q = lane >> 4;
  const int s = lane & 15;
  const int b = blockIdx.x, nb = b * 64;

  if (t < 64) hist[t] = 0;
  if (t == 0) gsteal = 0;
  __syncthreads();

  const int ecnt = min(bcnt[b], BCAP);
  const unsigned* pk = pck + (size_t)b * BCAP;
  unsigned ploc[5];
  int myn = 0;
  for (int i = t; i < ecnt; i += 256) {
    unsigned p = pk[i];
    ploc[myn++] = p;
    atomicAdd(&hist[p & 63u], 1);
  }
  __syncthreads();

  int c0 = (t < 64) ? hist[t] : 0;
  int pc = (c0 + 3) & ~3;
  int x = pc;
  if (t < 64) scanb[t] = x;
  __syncthreads();
  for (int d = 1; d < 64; d <<= 1) {
    int y = (t >= d && t < 64) ? scanb[t - d] : 0;
    __syncthreads();
    if (t < 64) { x += y; scanb[t] = x; }
    __syncthreads();
  }
  if (t < 64) { pexcl[t] = x - pc; curs[t] = x - pc; }
  __syncthreads();

  for (int k = 0; k < myn; ++k) {
    unsigned p = ploc[k];
    int r = atomicAdd(&curs[p & 63u], 1);
    ssrcL[r] = (int)(p >> 6);
  }
  if (t < 64)
    for (int j = c0; j < pc; ++j) ssrcL[pexcl[t] + j] = N;   // disjoint pad slots
  __syncthreads();

  // dump sorted list + meta for fusedC
  for (int i = t; i < PADC; i += 256) srt[(size_t)b * PADC + i] = ssrcL[i];
  if (t < 64) meta[b * 64 + t] = (pexcl[t] << 16) | hist[t];

  // steal-gather: each wave grabs 8 nodes (one per 8-lane group); 8-deep uint4
  const int s8 = lane & 7;
  const int g8 = lane >> 3;
  const unsigned char* Pb = P1 + (size_t)s8 * 16;
  for (;;) {
    int n8;
    if (lane == 0) n8 = atomicAdd(&gsteal, 8);
    n8 = __shfl(n8, 0, 64);
    if (n8 >= 64) break;
    int dl = n8 + g8;
    int node = nb + dl;
    int start = pexcl[dl];
    int dg = hist[dl];
    int pend = start + ((dg + 3) & ~3);

    f32x2 a01 = {0.f, 0.f}, a23 = {0.f, 0.f}, a45 = {0.f, 0.f}, a67 = {0.f, 0.f};
    f32x2 a89 = {0.f, 0.f}, aAB = {0.f, 0.f}, aCD = {0.f, 0.f}, aEF = {0.f, 0.f};
    int cur = start;
    for (; cur + 8 <= pend; cur += 8) {
      int4 sv0 = *(const int4*)&ssrcL[cur];       // LDS broadcast (16B-aligned)
      int4 sv1 = *(const int4*)&ssrcL[cur + 4];
      uint4 v0 = *(const uint4*)(Pb + (size_t)sv0.x * 128);
      uint4 v1 = *(const uint4*)(Pb + (size_t)sv0.y * 128);
      uint4 v2 = *(const uint4*)(Pb + (size_t)sv0.z * 128);
      uint4 v3 = *(const uint4*)(Pb + (size_t)sv0.w * 128);
      uint4 v4 = *(const uint4*)(Pb + (size_t)sv1.x * 128);
      uint4 v5 = *(const uint4*)(Pb + (size_t)sv1.y * 128);
      uint4 v6 = *(const uint4*)(Pb + (size_t)sv1.z * 128);
      uint4 v7 = *(const uint4*)(Pb + (size_t)sv1.w * 128);
      ACC16(v0) ACC16(v1) ACC16(v2) ACC16(v3)
      ACC16(v4) ACC16(v5) ACC16(v6) ACC16(v7)
    }
    if (cur < pend) {                             // remainder is 0 or 4
      int4 sv = *(const int4*)&ssrcL[cur];
      uint4 v0 = *(const uint4*)(Pb + (size_t)sv.x * 128);
      uint4 v1 = *(const uint4*)(Pb + (size_t)sv.y * 128);
      uint4 v2 = *(const uint4*)(Pb + (size_t)sv.z * 128);
      uint4 v3 = *(const uint4*)(Pb + (size_t)sv.w * 128);
      ACC16(v0) ACC16(v1) ACC16(v2) ACC16(v3)
    }

    int nc = min(node, N - 1);
    float inv = 1.0f / (float)(dg > 0 ? dg : 1);
    const int p16 = s8 * 16;
    bf16x8 rv0 = *(const bf16x8*)&R[(size_t)nc * 128 + p16];
    bf16x8 rv1 = *(const bf16x8*)&R[(size_t)nc * 128 + p16 + 8];
    float ac[16] = {a01[0], a01[1], a23[0], a23[1], a45[0], a45[1], a67[0], a67[1],
                    a89[0], a89[1], aAB[0], aAB[1], aCD[0], aCD[1], aEF[0], aEF[1]};
    bf16x8 h0, h1;
#pragma unroll
    for (int j = 0; j < 8; ++j) {
      h0[j] = (__bf16)fmaxf(ac[j] * inv + (float)rv0[j], 0.f);
      h1[j] = (__bf16)fmaxf(ac[8 + j] * inv + (float)rv1[j], 0.f);
    }
    *(bf16x8*)&Hlds[dl][p16] = h0;
    *(bf16x8*)&Hlds[dl][p16 + 8] = h1;
  }
  __syncthreads();

  float breg[4];
#pragma unroll
  for (int j = 0; j < 4; ++j)
    breg[j] = (w >= 2) ? bias[((w - 2) * 4 + j) * 16 + s] : 0.f;

  // GEMM: [P2|R2] = H @ Ws2 (+b2), 64x256, 2 half-passes over row-tiles
#pragma unroll
  for (int half = 0; half < 2; ++half) {
    f32x4 acc[8];
    f32x4 zero = {0.f, 0.f, 0.f, 0.f};
#pragma unroll
    for (int i = 0; i < 8; ++i) acc[i] = zero;

#pragma unroll
    for (int c = 0; c < 4; ++c) {
      bf16x8 a0 = *(const bf16x8*)&Hlds[(half * 2 + 0) * 16 + s][c * 32 + q * 8];
      bf16x8 a1 = *(const bf16x8*)&Hlds[(half * 2 + 1) * 16 + s][c * 32 + q * 8];
#pragma unroll
      for (int ct = 0; ct < 4; ++ct) {
        bf16x8 b = *(const bf16x8*)&Wswz[(size_t)((((w * 4 + ct) * 4 + c) * 64) + lane) * 8];
        acc[ct]     = __builtin_amdgcn_mfma_f32_16x16x32_bf16(a0, b, acc[ct], 0, 0, 0);
        acc[4 + ct] = __builtin_amdgcn_mfma_f32_16x16x32_bf16(a1, b, acc[4 + ct], 0, 0, 0);
      }
    }

#pragma unroll
    for (int i = 0; i < 2; ++i) {
      int rt = half * 2 + i;
#pragma unroll
      for (int r = 0; r < 4; ++r) {
        int row = nb + rt * 16 + q * 4 + r;
        if (row < N) {
          if (w < 2) {
            unsigned v = 0;
            v = __builtin_amdgcn_cvt_pk_fp8_f32(acc[i * 4 + 0][r], acc[i * 4 + 1][r], v, false);
            v = __builtin_amdgcn_cvt_pk_fp8_f32(acc[i * 4 + 2][r], acc[i * 4 + 3][r], v, true);
            *(unsigned*)&P2[(size_t)row * 128 + s * 8 + w * 4] = v;
          } else {
            bf16x4 o;
#pragma unroll
            for (int ct = 0; ct < 4; ++ct) o[ct] = (__bf16)(acc[i * 4 + ct][r] + breg[ct]);
            *(bf16x4*)&R[(size_t)row * 128 + s * 8 + (w - 2) * 4] = o;
          }
        }
      }
    }
  }
}

// ------- K4: fusedC: presorted 8-lane uint4 steal-gather(P2) -> heads -> out -------
// NO MFMA => no AGPR carve => (256,6) safe (R19), ~40-45% occupancy.

__global__ __launch_bounds__(256, 6) void fusedC_kernel(
    const unsigned char* __restrict__ P2, const __bf16* __restrict__ R,
    const int* __restrict__ srt, const int* __restrict__ meta,
    float* __restrict__ out,
    const float* __restrict__ Wp, const float* __restrict__ Wd,
    const float* __restrict__ bp, const float* __restrict__ bd, int N) {
  __shared__ int ssrcL[PADC];
  __shared__ int hist[64], pexcl[64];
  __shared__ int gsteal;
  const int t = threadIdx.x;
  const int lane = t & 63;
  const int b = blockIdx.x, nb = b * 64;

  for (int i = t; i < PADC; i += 256) ssrcL[i] = srt[(size_t)b * PADC + i];
  if (t < 64) {
    int m = meta[b * 64 + t];
    pexcl[t] = m >> 16;
    hist[t] = m & 0xffff;
  }
  if (t == 0) gsteal = 0;
  __syncthreads();

  const int s8 = lane & 7;
  const int g8 = lane >> 3;
  const unsigned char* Pb = P2 + (size_t)s8 * 16;
  for (;;) {
    int n8;
    if (lane == 0) n8 = atomicAdd(&gsteal, 8);
    n8 = __shfl(n8, 0, 64);
    if (n8 >= 64) break;
    int dl = n8 + g8;
    int node = nb + dl;
    int start = pexcl[dl];
    int dg = hist[dl];
    int pend = start + ((dg + 3) & ~3);

    f32x2 a01 = {0.f, 0.f}, a23 = {0.f, 0.f}, a45 = {0.f, 0.f}, a67 = {0.f, 0.f};
    f32x2 a89 = {0.f, 0.f}, aAB = {0.f, 0.f}, aCD = {0.f, 0.f}, aEF = {0.f, 0.f};
    for (int cur = start; cur < pend; cur += 4) {
      int4 sv = *(const int4*)&ssrcL[cur];
      uint4 v0 = *(const uint4*)(Pb + (size_t)sv.x * 128);
      uint4 v1 = *(const uint4*)(Pb + (size_t)sv.y * 128);
      uint4 v2 = *(const uint4*)(Pb + (size_t)sv.z * 128);
      uint4 v3 = *(const uint4*)(Pb + (size_t)sv.w * 128);
      ACC16(v0) ACC16(v1) ACC16(v2) ACC16(v3)
    }

    int nc = min(node, N - 1);
    float inv = 1.0f / (float)(dg > 0 ? dg : 1);
    const int p16 = s8 * 16;
    bf16x8 rv0 = *(const bf16x8*)&R[(size_t)nc * 128 + p16];
    bf16x8 rv1 = *(const bf16x8*)&R[(size_t)nc * 128 + p16 + 8];
    float ac[16] = {a01[0], a01[1], a23[0], a23[1], a45[0], a45[1], a67[0], a67[1],
                    a89[0], a89[1], aAB[0], aAB[1], aCD[0], aCD[1], aEF[0], aEF[1]};
    float p = 0.f, dd = 0.f;
#pragma unroll
    for (int j = 0; j < 16; ++j) {
      int pos = p16 + j;
      int f = ((pos & 7) << 4) | (pos >> 3);     // inverse feature perm
      float rvj = (float)((j < 8) ? rv0[j] : rv1[j - 8]);
      float h = fmaxf(ac[j] * inv + rvj, 0.f);
      p += h * Wp[f];
      dd += h * Wd[f];
    }
    p += __shfl_xor(p, 1, 64);  p += __shfl_xor(p, 2, 64);  p += __shfl_xor(p, 4, 64);
    dd += __shfl_xor(dd, 1, 64); dd += __shfl_xor(dd, 2, 64); dd += __shfl_xor(dd, 4, 64);
    if (node < N && s8 == 0) {
      float preds = p + bp[0];
      float sg = 1.0f / (1.0f + __expf(-(dd + bd[0])));
      out[node] = preds - sg;
      out[N + node] = preds + sg;
    }
  }
}

// ----------------------------------- launch -----------------------------------

extern "C" void kernel_launch(void* const* d_in, const int* in_sizes, int n_in,
                              void* d_out, int out_size, void* d_ws, size_t ws_size,
                              hipStream_t stream) {
  const float* x    = (const float*)d_in[0];
  const int*   ei   = (const int*)d_in[1];
  const float* Wl1 = (const float*)d_in[2];
  const float* Wr1 = (const float*)d_in[3];
  const float* b1  = (const float*)d_in[4];
  const float* Wl2 = (const float*)d_in[5];
  const float* Wr2 = (const float*)d_in[6];
  const float* b2  = (const float*)d_in[7];
  const float* Wp  = (const float*)d_in[8];
  const float* bp  = (const float*)d_in[9];
  const float* Wd  = (const float*)d_in[10];
  const float* bd  = (const float*)d_in[11];
  float* out = (float*)d_out;

  const int N = N_NODES, E = N_EDGES;
  const int* src = ei;
  const int* dst = ei + E;

  char* w = (char*)d_ws;
  unsigned char* P1 = (unsigned char*)w; w += (size_t)(N + 1) * 128;  // fp8 + sentinel
  unsigned char* P2 = (unsigned char*)w; w += (size_t)(N + 1) * 128;  // fp8 + sentinel
  __bf16* Rbuf   = (__bf16*)w;   w += (size_t)N * 128 * 2;            // R1 -> R2 in place
  unsigned* pck  = (unsigned*)w; w += (size_t)NBUCK * BCAP * 4;       // 7.6 MB
  int* bcnt      = (int*)w;      w += (size_t)(NBUCK + 32) * 4;
  __bf16* Ws1    = (__bf16*)w;   w += 65536;
  __bf16* Ws2    = (__bf16*)w;   w += 65536;
  int* srt       = (int*)w;      w += (size_t)NBUCK * PADC * 4;       // 8.8 MB
  int* meta      = (int*)w;      w += (size_t)NBUCK * 64 * 4;         // 0.4 MB

  // K1: init + weight swizzle
  init_kernel<<<257, 256, 0, stream>>>(bcnt,
                                       (int*)(P1 + (size_t)N * 128),
                                       (int*)(P2 + (size_t)N * 128),
                                       Wl1, Wr1, Wl2, Wr2, Ws1, Ws2);
  // K2: partA v2 (blocks 0..PABLK-1) || gemm1 (blocks PABLK..)
  work1_kernel<<<GTILES + PABLK, 256, 0, stream>>>(x, Ws1, b1, P1, Rbuf, N,
                                                   src, dst, bcnt, pck, E);
  // K3: per-bucket sort + dump + H1 aggregation + layer-2 GEMM
  fusedB_kernel<<<NBUCK, 256, 0, stream>>>(P1, Rbuf, pck, bcnt, Ws2, b2, P2,
                                           srt, meta, N);
  // K4: presorted gather + heads
  fusedC_kernel<<<NBUCK, 256, 0, stream>>>(P2, Rbuf, srt, meta, out,
                                           Wp, Wd, bp, bd, N);
}

// Round 10
// 224.704 us; speedup vs baseline: 3.3834x; 1.1770x over previous
//
#include <hip/hip_runtime.h>
#include <hip/hip_bf16.h>

#define N_NODES 100000
#define N_EDGES 1600000
#define NBUCK 1563         // ceil(N/64): bucket = 64-node dst range
#define BCAP 1216          // per-bucket capacity (mean 1024, +6 sigma)
#define PADC 1408          // LDS ssrc capacity incl. per-node x4 padding
#define ACHUNK 4096        // edges per partA block (R22: 391 blocks — parallelism
                           // beats write-amp; R9's 16K chunks = 98-block tail, +35 µs)
#define GTILES 1563        // gemm row tiles (= NBUCK)
#define PABLK 391          // ceil(E/ACHUNK) partA blocks

typedef __bf16 bf16x8 __attribute__((ext_vector_type(8)));
typedef __bf16 bf16x4 __attribute__((ext_vector_type(4)));
typedef float  f32x4  __attribute__((ext_vector_type(4)));
typedef float  f32x2  __attribute__((ext_vector_type(2)));

// Feature permutation for P/R rows: feature f lives at position
// pos(f) = (f&15)*8 + (f>>4); inverse f(pos) = ((pos&7)<<4) | (pos>>3).
// P1/P2 have N+1 rows: row N is an all-zero sentinel for padded edge slots.
//
// Session ledger:
// R13/R14/R17: any launch bound >4 waves/SIMD spills MFMA kernels (AGPR
//   carve shrinks arch budget). (256,6) ONLY safe for MFMA-free kernels.
// R20: persistent mega-kernel = one regalloc across phases -> forced spill.
// R21/R22: partA two-pass 16K chunks cut WRITE 79->59MB but cost 35 µs of
//   98-block tail — traffic was never partA's binding term. One-pass 4096.
// R16/R18 nulls: partA grid position; uint2 gather depth; sort cost.
// R5/R7: work1 W-prefetch regressed -> JIT W loads.
// R19: fusedB uint4 8-lane gather (8 rows/load-inst, 64 lines in flight).

// fp8x16 (uint4) -> 16 f32 accumulate
#define ACC16(v)                                             \
  a01 += __builtin_amdgcn_cvt_pk_f32_fp8((v).x, false);      \
  a23 += __builtin_amdgcn_cvt_pk_f32_fp8((v).x, true);       \
  a45 += __builtin_amdgcn_cvt_pk_f32_fp8((v).y, false);      \
  a67 += __builtin_amdgcn_cvt_pk_f32_fp8((v).y, true);       \
  a89 += __builtin_amdgcn_cvt_pk_f32_fp8((v).z, false);      \
  aAB += __builtin_amdgcn_cvt_pk_f32_fp8((v).z, true);       \
  aCD += __builtin_amdgcn_cvt_pk_f32_fp8((v).w, false);      \
  aEF += __builtin_amdgcn_cvt_pk_f32_fp8((v).w, true);

// ---------------- K1: init (zero bcnt/sentinels) + weight swizzle ----------------

__global__ __launch_bounds__(256) void init_kernel(int* __restrict__ bcnt,
                                                   int* __restrict__ P1s,
                                                   int* __restrict__ P2s,
                                                   const float* __restrict__ Wl1,
                                                   const float* __restrict__ Wr1,
                                                   const float* __restrict__ Wl2,
                                                   const float* __restrict__ Wr2,
                                                   __bf16* __restrict__ W1out,
                                                   __bf16* __restrict__ W2out) {
  const int b = blockIdx.x, t = threadIdx.x;
  if (b == 0) {
    for (int i = t; i < NBUCK; i += 256) bcnt[i] = 0;
    if (t < 32) { P1s[t] = 0; P2s[t] = 0; }   // 128 B fp8 sentinel rows
    return;
  }
  int gi = (b - 1) * 256 + t;                 // 0..65535
  bool L2 = gi >= 32768;
  int i = gi & 32767;
  int j = i & 7;
  int lane = (i >> 3) & 63;
  int c = (i >> 9) & 3;
  int tile = i >> 11;
  int k = c * 32 + ((lane >> 4) * 8) + j;
  int krow = L2 ? (((k & 7) << 4) | (k >> 3)) : k;
  int col = tile * 16 + (lane & 15);
  const float* Wl = L2 ? Wl2 : Wl1;
  const float* Wr = L2 ? Wr2 : Wr1;
  float v = (col < 128) ? Wl[krow * 128 + col] : Wr[krow * 128 + (col - 128)];
  (L2 ? W2out : W1out)[i] = (__bf16)v;
}

// ------- K2: blocks 0..PABLK-1: partA (one-pass) ; blocks PABLK..: gemm1 -------

__global__ __launch_bounds__(256, 4) void work1_kernel(
    const float* __restrict__ A, const __bf16* __restrict__ Wswz,
    const float* __restrict__ bias, unsigned char* __restrict__ P,
    __bf16* __restrict__ R, int M,
    const int* __restrict__ src, const int* __restrict__ dst,
    int* __restrict__ bcnt, unsigned* __restrict__ packed, int E) {
  __shared__ __align__(16) char smem[64 * 144 * 2];   // 18432 B, unioned
  const int t = threadIdx.x;

  if (blockIdx.x < PABLK) {
    // ---- partA: one-pass, 4096-edge chunk (R4 proven form) ----
    int* hist = (int*)smem;                 // NBUCK ints = 6252 B
    int* curs = (int*)(smem + 6272);        // NBUCK ints
    for (int i = t; i < NBUCK; i += 256) hist[i] = 0;
    __syncthreads();

    const int base = blockIdx.x * ACHUNK;
    const int lim = min(base + ACHUNK, E);

    int dloc[16], sloc[16];
    int myn = 0;
    for (int i = base + t; i < lim; i += 256) {
      dloc[myn] = dst[i];
      sloc[myn] = src[i];
      ++myn;
    }
    for (int k = 0; k < myn; ++k) atomicAdd(&hist[dloc[k] >> 6], 1);
    __syncthreads();

    for (int i = t; i < NBUCK; i += 256) {
      int h = hist[i];
      curs[i] = (h > 0) ? atomicAdd(&bcnt[i], h) : 0;
    }
    __syncthreads();

    for (int k = 0; k < myn; ++k) {
      int d = dloc[k];
      int b = d >> 6;
      int pos = atomicAdd(&curs[b], 1);
      if (pos < BCAP)
        packed[(size_t)b * BCAP + pos] = ((unsigned)sloc[k] << 6) | (unsigned)(d & 63);
    }
    return;
  }

  // ---- gemm1 path (R4 form: JIT W loads, no prefetch) ----
  __bf16 (*ldsA)[144] = (__bf16 (*)[144])smem;
  const int lane = t & 63;
  const int w = t >> 6;
  const int q = lane >> 4;
  const int s = lane & 15;
  const int m0 = (blockIdx.x - PABLK) * 64;

#pragma unroll
  for (int it = 0; it < 8; ++it) {
    int row = it * 8 + (t >> 5);
    int col = (t & 31) * 4;
    float4 v = make_float4(0.f, 0.f, 0.f, 0.f);
    if (m0 + row < M) v = *(const float4*)&A[(size_t)(m0 + row) * 128 + col];
    bf16x4 bv;
    bv.x = (__bf16)v.x; bv.y = (__bf16)v.y; bv.z = (__bf16)v.z; bv.w = (__bf16)v.w;
    *(bf16x4*)&ldsA[row][col] = bv;
  }

  float breg[4];
#pragma unroll
  for (int j = 0; j < 4; ++j)
    breg[j] = (w >= 2) ? bias[((w - 2) * 4 + j) * 16 + s] : 0.f;

  __syncthreads();

#pragma unroll
  for (int half = 0; half < 2; ++half) {
    f32x4 acc[8];                       // 2 row-tiles x 4 col-tiles
    f32x4 zero = {0.f, 0.f, 0.f, 0.f};
#pragma unroll
    for (int i = 0; i < 8; ++i) acc[i] = zero;

#pragma unroll
    for (int c = 0; c < 4; ++c) {
      bf16x8 a0 = *(const bf16x8*)&ldsA[(half * 2 + 0) * 16 + s][c * 32 + q * 8];
      bf16x8 a1 = *(const bf16x8*)&ldsA[(half * 2 + 1) * 16 + s][c * 32 + q * 8];
#pragma unroll
      for (int ct = 0; ct < 4; ++ct) {
        bf16x8 b = *(const bf16x8*)&Wswz[(size_t)((((w * 4 + ct) * 4 + c) * 64) + lane) * 8];
        acc[ct]     = __builtin_amdgcn_mfma_f32_16x16x32_bf16(a0, b, acc[ct], 0, 0, 0);
        acc[4 + ct] = __builtin_amdgcn_mfma_f32_16x16x32_bf16(a1, b, acc[4 + ct], 0, 0, 0);
      }
    }

#pragma unroll
    for (int i = 0; i < 2; ++i) {
      int rt = half * 2 + i;
#pragma unroll
      for (int r = 0; r < 4; ++r) {
        int row = m0 + rt * 16 + q * 4 + r;
        if (row < M) {
          if (w < 2) {
            unsigned v = 0;
            v = __builtin_amdgcn_cvt_pk_fp8_f32(acc[i * 4 + 0][r], acc[i * 4 + 1][r], v, false);
            v = __builtin_amdgcn_cvt_pk_fp8_f32(acc[i * 4 + 2][r], acc[i * 4 + 3][r], v, true);
            *(unsigned*)&P[(size_t)row * 128 + s * 8 + w * 4] = v;
          } else {
            bf16x4 o;
#pragma unroll
            for (int ct = 0; ct < 4; ++ct) o[ct] = (__bf16)(acc[i * 4 + ct][r] + breg[ct]);
            *(bf16x4*)&R[(size_t)row * 128 + s * 8 + (w - 2) * 4] = o;
          }
        }
      }
    }
  }
}

// ------- K3: fusedB: sort + dump + 8-lane uint4 steal-gather(P1) -> H1 -> [P2|R2] -------

__global__ __launch_bounds__(256, 4) void fusedB_kernel(
    const unsigned char* __restrict__ P1, __bf16* R,
    const unsigned* __restrict__ pck, const int* __restrict__ bcnt,
    const __bf16* __restrict__ Wswz, const float* __restrict__ bias,
    unsigned char* __restrict__ P2, int* __restrict__ srt,
    int* __restrict__ meta, int N) {
  __shared__ __bf16 Hlds[64][144];
  __shared__ int ssrcL[PADC];
  __shared__ int hist[64], pexcl[64], curs[64], scanb[64];
  __shared__ int gsteal;
  const int t = threadIdx.x;
  const int lane = t & 63;
  const int w = t >> 6;
  const int q = lane >> 4;
  const int s = lane & 15;
  const int b = blockIdx.x, nb = b * 64;

  if (t < 64) hist[t] = 0;
  if (t == 0) gsteal = 0;
  __syncthreads();

  const int ecnt = min(bcnt[b], BCAP);
  const unsigned* pk = pck + (size_t)b * BCAP;
  unsigned ploc[5];
  int myn = 0;
  for (int i = t; i < ecnt; i += 256) {
    unsigned p = pk[i];
    ploc[myn++] = p;
    atomicAdd(&hist[p & 63u], 1);
  }
  __syncthreads();

  int c0 = (t < 64) ? hist[t] : 0;
  int pc = (c0 + 3) & ~3;
  int x = pc;
  if (t < 64) scanb[t] = x;
  __syncthreads();
  for (int d = 1; d < 64; d <<= 1) {
    int y = (t >= d && t < 64) ? scanb[t - d] : 0;
    __syncthreads();
    if (t < 64) { x += y; scanb[t] = x; }
    __syncthreads();
  }
  if (t < 64) { pexcl[t] = x - pc; curs[t] = x - pc; }
  __syncthreads();

  for (int k = 0; k < myn; ++k) {
    unsigned p = ploc[k];
    int r = atomicAdd(&curs[p & 63u], 1);
    ssrcL[r] = (int)(p >> 6);
  }
  if (t < 64)
    for (int j = c0; j < pc; ++j) ssrcL[pexcl[t] + j] = N;   // disjoint pad slots
  __syncthreads();

  // dump sorted list + meta for fusedC
  for (int i = t; i < PADC; i += 256) srt[(size_t)b * PADC + i] = ssrcL[i];
  if (t < 64) meta[b * 64 + t] = (pexcl[t] << 16) | hist[t];

  // steal-gather: each wave grabs 8 nodes (one per 8-lane group); 8-deep uint4
  const int s8 = lane & 7;
  const int g8 = lane >> 3;
  const unsigned char* Pb = P1 + (size_t)s8 * 16;
  for (;;) {
    int n8;
    if (lane == 0) n8 = atomicAdd(&gsteal, 8);
    n8 = __shfl(n8, 0, 64);
    if (n8 >= 64) break;
    int dl = n8 + g8;
    int node = nb + dl;
    int start = pexcl[dl];
    int dg = hist[dl];
    int pend = start + ((dg + 3) & ~3);

    f32x2 a01 = {0.f, 0.f}, a23 = {0.f, 0.f}, a45 = {0.f, 0.f}, a67 = {0.f, 0.f};
    f32x2 a89 = {0.f, 0.f}, aAB = {0.f, 0.f}, aCD = {0.f, 0.f}, aEF = {0.f, 0.f};
    int cur = start;
    for (; cur + 8 <= pend; cur += 8) {
      int4 sv0 = *(const int4*)&ssrcL[cur];       // LDS broadcast (16B-aligned)
      int4 sv1 = *(const int4*)&ssrcL[cur + 4];
      uint4 v0 = *(const uint4*)(Pb + (size_t)sv0.x * 128);
      uint4 v1 = *(const uint4*)(Pb + (size_t)sv0.y * 128);
      uint4 v2 = *(const uint4*)(Pb + (size_t)sv0.z * 128);
      uint4 v3 = *(const uint4*)(Pb + (size_t)sv0.w * 128);
      uint4 v4 = *(const uint4*)(Pb + (size_t)sv1.x * 128);
      uint4 v5 = *(const uint4*)(Pb + (size_t)sv1.y * 128);
      uint4 v6 = *(const uint4*)(Pb + (size_t)sv1.z * 128);
      uint4 v7 = *(const uint4*)(Pb + (size_t)sv1.w * 128);
      ACC16(v0) ACC16(v1) ACC16(v2) ACC16(v3)
      ACC16(v4) ACC16(v5) ACC16(v6) ACC16(v7)
    }
    if (cur < pend) {                             // remainder is 0 or 4
      int4 sv = *(const int4*)&ssrcL[cur];
      uint4 v0 = *(const uint4*)(Pb + (size_t)sv.x * 128);
      uint4 v1 = *(const uint4*)(Pb + (size_t)sv.y * 128);
      uint4 v2 = *(const uint4*)(Pb + (size_t)sv.z * 128);
      uint4 v3 = *(const uint4*)(Pb + (size_t)sv.w * 128);
      ACC16(v0) ACC16(v1) ACC16(v2) ACC16(v3)
    }

    int nc = min(node, N - 1);
    float inv = 1.0f / (float)(dg > 0 ? dg : 1);
    const int p16 = s8 * 16;
    bf16x8 rv0 = *(const bf16x8*)&R[(size_t)nc * 128 + p16];
    bf16x8 rv1 = *(const bf16x8*)&R[(size_t)nc * 128 + p16 + 8];
    float ac[16] = {a01[0], a01[1], a23[0], a23[1], a45[0], a45[1], a67[0], a67[1],
                    a89[0], a89[1], aAB[0], aAB[1], aCD[0], aCD[1], aEF[0], aEF[1]};
    bf16x8 h0, h1;
#pragma unroll
    for (int j = 0; j < 8; ++j) {
      h0[j] = (__bf16)fmaxf(ac[j] * inv + (float)rv0[j], 0.f);
      h1[j] = (__bf16)fmaxf(ac[8 + j] * inv + (float)rv1[j], 0.f);
    }
    *(bf16x8*)&Hlds[dl][p16] = h0;
    *(bf16x8*)&Hlds[dl][p16 + 8] = h1;
  }
  __syncthreads();

  float breg[4];
#pragma unroll
  for (int j = 0; j < 4; ++j)
    breg[j] = (w >= 2) ? bias[((w - 2) * 4 + j) * 16 + s] : 0.f;

  // GEMM: [P2|R2] = H @ Ws2 (+b2), 64x256, 2 half-passes over row-tiles
#pragma unroll
  for (int half = 0; half < 2; ++half) {
    f32x4 acc[8];
    f32x4 zero = {0.f, 0.f, 0.f, 0.f};
#pragma unroll
    for (int i = 0; i < 8; ++i) acc[i] = zero;

#pragma unroll
    for (int c = 0; c < 4; ++c) {
      bf16x8 a0 = *(const bf16x8*)&Hlds[(half * 2 + 0) * 16 + s][c * 32 + q * 8];
      bf16x8 a1 = *(const bf16x8*)&Hlds[(half * 2 + 1) * 16 + s][c * 32 + q * 8];
#pragma unroll
      for (int ct = 0; ct < 4; ++ct) {
        bf16x8 b = *(const bf16x8*)&Wswz[(size_t)((((w * 4 + ct) * 4 + c) * 64) + lane) * 8];
        acc[ct]     = __builtin_amdgcn_mfma_f32_16x16x32_bf16(a0, b, acc[ct], 0, 0, 0);
        acc[4 + ct] = __builtin_amdgcn_mfma_f32_16x16x32_bf16(a1, b, acc[4 + ct], 0, 0, 0);
      }
    }

#pragma unroll
    for (int i = 0; i < 2; ++i) {
      int rt = half * 2 + i;
#pragma unroll
      for (int r = 0; r < 4; ++r) {
        int row = nb + rt * 16 + q * 4 + r;
        if (row < N) {
          if (w < 2) {
            unsigned v = 0;
            v = __builtin_amdgcn_cvt_pk_fp8_f32(acc[i * 4 + 0][r], acc[i * 4 + 1][r], v, false);
            v = __builtin_amdgcn_cvt_pk_fp8_f32(acc[i * 4 + 2][r], acc[i * 4 + 3][r], v, true);
            *(unsigned*)&P2[(size_t)row * 128 + s * 8 + w * 4] = v;
          } else {
            bf16x4 o;
#pragma unroll
            for (int ct = 0; ct < 4; ++ct) o[ct] = (__bf16)(acc[i * 4 + ct][r] + breg[ct]);
            *(bf16x4*)&R[(size_t)row * 128 + s * 8 + (w - 2) * 4] = o;
          }
        }
      }
    }
  }
}

// ------- K4: fusedC: presorted 8-lane uint4 steal-gather(P2) -> heads -> out -------
// NO MFMA => no AGPR carve => (256,6) safe (R19).

__global__ __launch_bounds__(256, 6) void fusedC_kernel(
    const unsigned char* __restrict__ P2, const __bf16* __restrict__ R,
    const int* __restrict__ srt, const int* __restrict__ meta,
    float* __restrict__ out,
    const float* __restrict__ Wp, const float* __restrict__ Wd,
    const float* __restrict__ bp, const float* __restrict__ bd, int N) {
  __shared__ int ssrcL[PADC];
  __shared__ int hist[64], pexcl[64];
  __shared__ int gsteal;
  const int t = threadIdx.x;
  const int lane = t & 63;
  const int b = blockIdx.x, nb = b * 64;

  for (int i = t; i < PADC; i += 256) ssrcL[i] = srt[(size_t)b * PADC + i];
  if (t < 64) {
    int m = meta[b * 64 + t];
    pexcl[t] = m >> 16;
    hist[t] = m & 0xffff;
  }
  if (t == 0) gsteal = 0;
  __syncthreads();

  const int s8 = lane & 7;
  const int g8 = lane >> 3;
  const unsigned char* Pb = P2 + (size_t)s8 * 16;
  for (;;) {
    int n8;
    if (lane == 0) n8 = atomicAdd(&gsteal, 8);
    n8 = __shfl(n8, 0, 64);
    if (n8 >= 64) break;
    int dl = n8 + g8;
    int node = nb + dl;
    int start = pexcl[dl];
    int dg = hist[dl];
    int pend = start + ((dg + 3) & ~3);

    f32x2 a01 = {0.f, 0.f}, a23 = {0.f, 0.f}, a45 = {0.f, 0.f}, a67 = {0.f, 0.f};
    f32x2 a89 = {0.f, 0.f}, aAB = {0.f, 0.f}, aCD = {0.f, 0.f}, aEF = {0.f, 0.f};
    for (int cur = start; cur < pend; cur += 4) {
      int4 sv = *(const int4*)&ssrcL[cur];
      uint4 v0 = *(const uint4*)(Pb + (size_t)sv.x * 128);
      uint4 v1 = *(const uint4*)(Pb + (size_t)sv.y * 128);
      uint4 v2 = *(const uint4*)(Pb + (size_t)sv.z * 128);
      uint4 v3 = *(const uint4*)(Pb + (size_t)sv.w * 128);
      ACC16(v0) ACC16(v1) ACC16(v2) ACC16(v3)
    }

    int nc = min(node, N - 1);
    float inv = 1.0f / (float)(dg > 0 ? dg : 1);
    const int p16 = s8 * 16;
    bf16x8 rv0 = *(const bf16x8*)&R[(size_t)nc * 128 + p16];
    bf16x8 rv1 = *(const bf16x8*)&R[(size_t)nc * 128 + p16 + 8];
    float ac[16] = {a01[0], a01[1], a23[0], a23[1], a45[0], a45[1], a67[0], a67[1],
                    a89[0], a89[1], aAB[0], aAB[1], aCD[0], aCD[1], aEF[0], aEF[1]};
    float p = 0.f, dd = 0.f;
#pragma unroll
    for (int j = 0; j < 16; ++j) {
      int pos = p16 + j;
      int f = ((pos & 7) << 4) | (pos >> 3);     // inverse feature perm
      float rvj = (float)((j < 8) ? rv0[j] : rv1[j - 8]);
      float h = fmaxf(ac[j] * inv + rvj, 0.f);
      p += h * Wp[f];
      dd += h * Wd[f];
    }
    p += __shfl_xor(p, 1, 64);  p += __shfl_xor(p, 2, 64);  p += __shfl_xor(p, 4, 64);
    dd += __shfl_xor(dd, 1, 64); dd += __shfl_xor(dd, 2, 64); dd += __shfl_xor(dd, 4, 64);
    if (node < N && s8 == 0) {
      float preds = p + bp[0];
      float sg = 1.0f / (1.0f + __expf(-(dd + bd[0])));
      out[node] = preds - sg;
      out[N + node] = preds + sg;
    }
  }
}

// ----------------------------------- launch -----------------------------------

extern "C" void kernel_launch(void* const* d_in, const int* in_sizes, int n_in,
                              void* d_out, int out_size, void* d_ws, size_t ws_size,
                              hipStream_t stream) {
  const float* x    = (const float*)d_in[0];
  const int*   ei   = (const int*)d_in[1];
  const float* Wl1 = (const float*)d_in[2];
  const float* Wr1 = (const float*)d_in[3];
  const float* b1  = (const float*)d_in[4];
  const float* Wl2 = (const float*)d_in[5];
  const float* Wr2 = (const float*)d_in[6];
  const float* b2  = (const float*)d_in[7];
  const float* Wp  = (const float*)d_in[8];
  const float* bp  = (const float*)d_in[9];
  const float* Wd  = (const float*)d_in[10];
  const float* bd  = (const float*)d_in[11];
  float* out = (float*)d_out;

  const int N = N_NODES, E = N_EDGES;
  const int* src = ei;
  const int* dst = ei + E;

  char* w = (char*)d_ws;
  unsigned char* P1 = (unsigned char*)w; w += (size_t)(N + 1) * 128;  // fp8 + sentinel
  unsigned char* P2 = (unsigned char*)w; w += (size_t)(N + 1) * 128;  // fp8 + sentinel
  __bf16* Rbuf   = (__bf16*)w;   w += (size_t)N * 128 * 2;            // R1 -> R2 in place
  unsigned* pck  = (unsigned*)w; w += (size_t)NBUCK * BCAP * 4;       // 7.6 MB
  int* bcnt      = (int*)w;      w += (size_t)(NBUCK + 32) * 4;
  __bf16* Ws1    = (__bf16*)w;   w += 65536;
  __bf16* Ws2    = (__bf16*)w;   w += 65536;
  int* srt       = (int*)w;      w += (size_t)NBUCK * PADC * 4;       // 8.8 MB
  int* meta      = (int*)w;      w += (size_t)NBUCK * 64 * 4;         // 0.4 MB

  // K1: init + weight swizzle
  init_kernel<<<257, 256, 0, stream>>>(bcnt,
                                       (int*)(P1 + (size_t)N * 128),
                                       (int*)(P2 + (size_t)N * 128),
                                       Wl1, Wr1, Wl2, Wr2, Ws1, Ws2);
  // K2: partA (blocks 0..PABLK-1) || gemm1 (blocks PABLK..)
  work1_kernel<<<GTILES + PABLK, 256, 0, stream>>>(x, Ws1, b1, P1, Rbuf, N,
                                                   src, dst, bcnt, pck, E);
  // K3: per-bucket sort + dump + H1 aggregation + layer-2 GEMM
  fusedB_kernel<<<NBUCK, 256, 0, stream>>>(P1, Rbuf, pck, bcnt, Ws2, b2, P2,
                                           srt, meta, N);
  // K4: presorted gather + heads
  fusedC_kernel<<<NBUCK, 256, 0, stream>>>(P2, Rbuf, srt, meta, out,
                                           Wp, Wd, bp, bd, N);
}